// Round 7
// baseline (269.613 us; speedup 1.0000x reference)
//
#include <hip/hip_runtime.h>
#include <hip/hip_bf16.h>

// B=2, T=2048, C=1024, H=16, HD=64. f32 I/O; bf16 MFMA internally, f32 accum.
//
//   0) pack_bf16: x -> xb bf16; transpose_pack: w_qkv,w_out -> bf16 W^T[N][K]
//   1) gemm_glds<EPI=1,BN=128>: qkv proj; Q pre-scaled 0.125*log2e -> qk,
//      K -> qk, V -> vt[B,H,64,T] (pre-transposed).
//   2) attn_mfma: flash attention, static exp2 softmax, 4-wave blocks:
//      wave w owns hi tile 127-(4p+w) (nch=32-p) + lo tile 4p+w (nch=p+1)
//      -- uniform per-wave work (33 tiles), 16 waves/CU at launch_bounds(256,4).
//   3) gemm_glds<EPI=0,BN=64>: out proj, grid 512 (2 blocks/CU) -> d_out f32

#define B_ 2
#define T_ 2048
#define C_ 1024
#define H_ 16
#define HD_ 64
#define M_ (B_ * T_)      // 4096
#define N3_ (3 * C_)      // 3072
#define QK2_ 2048
#define QSCALE 0.18033688f   // 0.125 * log2(e)

typedef __attribute__((ext_vector_type(8))) short short8;
typedef __attribute__((ext_vector_type(4))) short short4v;
typedef __attribute__((ext_vector_type(4))) float floatx4;

__device__ __forceinline__ unsigned short f2b(float f) {
    __hip_bfloat16 h = __float2bfloat16(f);
    return *reinterpret_cast<unsigned short*>(&h);
}

__device__ __forceinline__ void glds16(const void* g, void* l) {
    __builtin_amdgcn_global_load_lds(
        (const __attribute__((address_space(1))) void*)g,
        (__attribute__((address_space(3))) void*)l, 16, 0, 0);
}

// f32 -> bf16 elementwise (x pack)
__global__ __launch_bounds__(256) void pack_bf16(
    const float* __restrict__ src, unsigned short* __restrict__ dst) {
    int i = (blockIdx.x * 256 + threadIdx.x) * 4;
    float4 v = *reinterpret_cast<const float4*>(src + i);
    short4v s;
    s[0] = (short)f2b(v.x); s[1] = (short)f2b(v.y);
    s[2] = (short)f2b(v.z); s[3] = (short)f2b(v.w);
    *reinterpret_cast<short4v*>(dst + i) = s;
}

// src[K][N] f32 -> dst[N][K] bf16
__global__ __launch_bounds__(256) void transpose_pack(
    const float* __restrict__ src, unsigned short* __restrict__ dst,
    int K, int N) {
    __shared__ float t[32][33];
    const int n0 = blockIdx.x * 32, k0 = blockIdx.y * 32;
    const int tx = threadIdx.x & 31, ty = threadIdx.x >> 5;
#pragma unroll
    for (int i = 0; i < 4; i++)
        t[ty + i * 8][tx] = src[(size_t)(k0 + ty + i * 8) * N + n0 + tx];
    __syncthreads();
#pragma unroll
    for (int i = 0; i < 4; i++)
        dst[(size_t)(n0 + ty + i * 8) * K + k0 + tx] = f2b(t[tx][ty + i * 8]);
}

// ---------------------------------------------------------------------------
// GEMM (m97 structure): C[M,N] = A[M,K] @ Bt^T[N,K] + bias[N]. A,Bt bf16.
// Tile 128 x BN, BK=32, 4 waves 2x2 (wave sub-tile 64 x BN/2).
// LDS unpadded [rows][32] shorts; global_load_lds width=16 is exactly
// row-major; frag b128 reads at 32-short stride are conflict-free.
// EPI=0: f32 C.  EPI=1 (BN=128): Q(scaled)/K -> qk bf16; V -> vt[B,H,64,T].
// ---------------------------------------------------------------------------
template<int EPI, int BN>
__global__ __launch_bounds__(256) void gemm_glds(
    const unsigned short* __restrict__ A, const unsigned short* __restrict__ Bt,
    const float* __restrict__ bias, void* __restrict__ Cp,
    unsigned short* __restrict__ vtp, int M, int N, int K) {
    constexpr int NI = BN / 32;            // in-tiles per wave
    __shared__ __align__(16) unsigned short Al[128 * 32];
    __shared__ __align__(16) unsigned short Bl[BN * 32];

    const int tid  = threadIdx.x;
    const int lane = tid & 63;
    const int w    = tid >> 6;
    const int c16  = lane & 15;
    const int quad = lane >> 4;
    const int n0 = blockIdx.x * BN;
    const int m0 = blockIdx.y * 128;
    const int wm = (w >> 1) * 64;
    const int wn = (w & 1) * (BN / 2);

    floatx4 acc[4][NI] = {};

    const int srow = w * 32 + (lane >> 2);
    const int scol = (lane & 3) * 8;
    const unsigned short* ag = A + (size_t)(m0 + srow) * K + scol;
    unsigned short* al0 = &Al[(w * 32) * 32];
    unsigned short* al1 = &Al[(w * 32 + 16) * 32];
    const int srowB = w * (BN / 4) + (lane >> 2);
    const unsigned short* bg = Bt + (size_t)(n0 + srowB) * K + scol;

    for (int k0 = 0; k0 < K; k0 += 32) {
        __syncthreads();
        glds16(ag + k0, al0);
        glds16(ag + k0 + (size_t)16 * K, al1);
#pragma unroll
        for (int i = 0; i < BN / 64; i++)
            glds16(bg + k0 + (size_t)(i * 16) * K,
                   &Bl[(w * (BN / 4) + i * 16) * 32]);
        __syncthreads();

        short8 af[4], bf[NI];
#pragma unroll
        for (int im = 0; im < 4; im++)
            af[im] = *reinterpret_cast<const short8*>(
                &Al[(wm + im * 16 + c16) * 32 + quad * 8]);
#pragma unroll
        for (int in = 0; in < NI; in++)
            bf[in] = *reinterpret_cast<const short8*>(
                &Bl[(wn + in * 16 + c16) * 32 + quad * 8]);
#pragma unroll
        for (int im = 0; im < 4; im++)
#pragma unroll
            for (int in = 0; in < NI; in++)
                acc[im][in] = __builtin_amdgcn_mfma_f32_16x16x32_bf16(
                    af[im], bf[in], acc[im][in], 0, 0, 0);
    }

    const int ncol = n0 + wn;
    float bv[NI];
#pragma unroll
    for (int in = 0; in < NI; in++) bv[in] = bias[ncol + in * 16 + c16];

    if (EPI == 0) {
        float* C = (float*)Cp;
#pragma unroll
        for (int im = 0; im < 4; im++)
#pragma unroll
            for (int r = 0; r < 4; r++) {
                int row = m0 + wm + im * 16 + quad * 4 + r;
#pragma unroll
                for (int in = 0; in < NI; in++)
                    C[(size_t)row * N + ncol + in * 16 + c16] =
                        acc[im][in][r] + bv[in];
            }
    } else {
        if (ncol < 2 * C_) {     // Q or K -> qk (wave-uniform branch)
            const float fac = (ncol < C_) ? QSCALE : 1.0f;
            unsigned short* qkp = (unsigned short*)Cp;
#pragma unroll
            for (int im = 0; im < 4; im++)
#pragma unroll
                for (int r = 0; r < 4; r++) {
                    int row = m0 + wm + im * 16 + quad * 4 + r;
#pragma unroll
                    for (int in = 0; in < NI; in++)
                        qkp[(size_t)row * QK2_ + ncol + in * 16 + c16] =
                            f2b((acc[im][in][r] + bv[in]) * fac);
                }
        } else {                 // V -> vt[B,H,64,T]
#pragma unroll
            for (int im = 0; im < 4; im++) {
                int row0 = m0 + wm + im * 16 + quad * 4;
                int b  = row0 >> 11;
                int t0 = row0 & (T_ - 1);
#pragma unroll
                for (int in = 0; in < NI; in++) {
                    int dfull = ncol - 2 * C_ + in * 16 + c16;  // h*64+d
                    short4v sv;
#pragma unroll
                    for (int r = 0; r < 4; r++)
                        sv[r] = (short)f2b(acc[im][in][r] + bv[in]);
                    *reinterpret_cast<short4v*>(
                        &vtp[(((size_t)(b << 10) + dfull) << 11) + t0]) = sv;
                }
            }
        }
    }
}

// ---------------------------------------------------------------------------
// One 16-row Q-tile x 64-key chunk: QK MFMAs, static exp2 softmax, per-lane
// l accumulation, P LDS round-trip (wave-private), PV MFMAs.
// ---------------------------------------------------------------------------
__device__ __forceinline__ void attn_tile(
    short8 af0, short8 af1,
    const unsigned short* __restrict__ Kl,
    const unsigned short* __restrict__ Vl,
    unsigned short* __restrict__ pw,
    floatx4 O[4], float lrow[4],
    int row0, int kb, int c16, int quad) {
    const floatx4 z = {0.f, 0.f, 0.f, 0.f};
    floatx4 s[4];
#pragma unroll
    for (int nt = 0; nt < 4; nt++) {
        short8 k0 = *reinterpret_cast<const short8*>(
            &Kl[(nt * 16 + c16) * 72 + quad * 8]);
        short8 k1 = *reinterpret_cast<const short8*>(
            &Kl[(nt * 16 + c16) * 72 + 32 + quad * 8]);
        floatx4 t = __builtin_amdgcn_mfma_f32_16x16x32_bf16(af0, k0, z, 0, 0, 0);
        s[nt] = __builtin_amdgcn_mfma_f32_16x16x32_bf16(af1, k1, t, 0, 0, 0);
    }
#pragma unroll
    for (int nt = 0; nt < 4; nt++)
#pragma unroll
        for (int r = 0; r < 4; r++) {
            int key = kb + nt * 16 + c16;
            int row = row0 + quad * 4 + r;
            float p = (key <= row) ? exp2f(s[nt][r]) : 0.f;
            lrow[r] += p;
            pw[(quad * 4 + r) * 72 + nt * 16 + c16] = f2b(p);
        }
    short8 pf0 = *reinterpret_cast<const short8*>(&pw[c16 * 72 + quad * 8]);
    short8 pf1 = *reinterpret_cast<const short8*>(&pw[c16 * 72 + 32 + quad * 8]);
#pragma unroll
    for (int nt = 0; nt < 4; nt++) {
        short8 v0 = *reinterpret_cast<const short8*>(
            &Vl[(nt * 16 + c16) * 72 + quad * 8]);
        short8 v1 = *reinterpret_cast<const short8*>(
            &Vl[(nt * 16 + c16) * 72 + 32 + quad * 8]);
        floatx4 t = __builtin_amdgcn_mfma_f32_16x16x32_bf16(pf0, v0, O[nt], 0, 0, 0);
        O[nt] = __builtin_amdgcn_mfma_f32_16x16x32_bf16(pf1, v1, t, 0, 0, 0);
    }
}

// ---------------------------------------------------------------------------
// Flash attention. 256-thr / 4-wave blocks; block p in [0,16) per bh; wave w
// owns hi tile 127-(4p+w) [nch = 32-p, block-uniform] and lo tile 4p+w
// [nch = p+1, uniform]. Per-wave work = 33 tiles exactly. Grid 512; adjacent
// blockIdx pairs carry complementary p (p, 15-p) to even per-CU makespan.
// launch_bounds(256,4): VGPR<=128 -> 2 blocks/CU = 16 waves/CU.
// ---------------------------------------------------------------------------
__global__ __launch_bounds__(256, 4) void attn_mfma(
    const unsigned short* __restrict__ qk,
    const unsigned short* __restrict__ vt,
    unsigned short* __restrict__ y) {
    __shared__ __align__(16) unsigned short Kl[64 * 72];
    __shared__ __align__(16) unsigned short Vl[64 * 72];
    __shared__ __align__(16) unsigned short Pl[4 * 16 * 72];

    const int tid  = threadIdx.x;
    const int lane = tid & 63;
    const int w    = tid >> 6;
    const int c16  = lane & 15;
    const int quad = lane >> 4;
    const int j16 = blockIdx.x & 15;
    const int bh  = blockIdx.x >> 4;
    int p = j16 >> 1;
    if (j16 & 1) p = 15 - p;              // complementary adjacent pairs
    const int b = bh >> 4;
    const int h = bh & 15;
    const int rhi0 = (127 - (4 * p + w)) * 16;
    const int rlo0 = (4 * p + w) * 16;
    const int nch    = 32 - p;            // hi nch == block loop bound
    const int nch_lo = p + 1;

    const unsigned short* qrow = qk + (size_t)b * T_ * QK2_ + h * HD_;
    const unsigned short* krow = qrow + C_;
    const unsigned short* vrow = vt + ((size_t)bh << 6) * T_;

    short8 afh0 = *reinterpret_cast<const short8*>(
        qrow + (size_t)(rhi0 + c16) * QK2_ + quad * 8);
    short8 afh1 = *reinterpret_cast<const short8*>(
        qrow + (size_t)(rhi0 + c16) * QK2_ + 32 + quad * 8);
    short8 afl0 = *reinterpret_cast<const short8*>(
        qrow + (size_t)(rlo0 + c16) * QK2_ + quad * 8);
    short8 afl1 = *reinterpret_cast<const short8*>(
        qrow + (size_t)(rlo0 + c16) * QK2_ + 32 + quad * 8);

    floatx4 Ohi[4] = {}, Olo[4] = {};
    float lhi[4] = {}, llo[4] = {};
    unsigned short* pw = &Pl[w * 16 * 72];

    for (int c = 0; c < nch; c++) {
        const int kb = c * 64;
        __syncthreads();                  // prev chunk's Kl/Vl reads complete
#pragma unroll
        for (int g = tid; g < 512; g += 256) {
            int r8 = g >> 3, o8 = g & 7;
            *reinterpret_cast<short8*>(&Kl[r8 * 72 + o8 * 8]) =
                *reinterpret_cast<const short8*>(
                    krow + (size_t)(kb + r8) * QK2_ + o8 * 8);
            *reinterpret_cast<short8*>(&Vl[r8 * 72 + o8 * 8]) =
                *reinterpret_cast<const short8*>(
                    vrow + (size_t)r8 * T_ + kb + o8 * 8);
        }
        __syncthreads();

        attn_tile(afh0, afh1, Kl, Vl, pw, Ohi, lhi, rhi0, kb, c16, quad);
        if (c < nch_lo)
            attn_tile(afl0, afl1, Kl, Vl, pw, Olo, llo, rlo0, kb, c16, quad);
    }

#pragma unroll
    for (int r = 0; r < 4; r++) {
#pragma unroll
        for (int off = 1; off < 16; off <<= 1) {
            lhi[r] += __shfl_xor(lhi[r], off);
            llo[r] += __shfl_xor(llo[r], off);
        }
    }

#pragma unroll
    for (int nt = 0; nt < 4; nt++)
#pragma unroll
        for (int r = 0; r < 4; r++) {
            float vh = Ohi[nt][r] / fmaxf(lhi[r], 1e-30f);
            y[((size_t)b * T_ + rhi0 + quad * 4 + r) * C_ + h * HD_ + nt * 16 + c16] =
                f2b(vh);
            float vl = Olo[nt][r] / fmaxf(llo[r], 1e-30f);
            y[((size_t)b * T_ + rlo0 + quad * 4 + r) * C_ + h * HD_ + nt * 16 + c16] =
                f2b(vl);
        }
}

extern "C" void kernel_launch(void* const* d_in, const int* in_sizes, int n_in,
                              void* d_out, int out_size, void* d_ws, size_t ws_size,
                              hipStream_t stream) {
    const float* x     = (const float*)d_in[0];
    const float* w_qkv = (const float*)d_in[1];
    const float* b_qkv = (const float*)d_in[2];
    const float* w_out = (const float*)d_in[3];
    const float* b_out = (const float*)d_in[4];
    float* out = (float*)d_out;

    unsigned short* qkb = (unsigned short*)d_ws;                 // [4096][2048]
    unsigned short* vtb = qkb + (size_t)M_ * QK2_;               // [B,H,64,T]
    unsigned short* yb  = vtb + (size_t)B_ * H_ * HD_ * T_;      // [4096][1024]
    unsigned short* wt1 = yb + (size_t)M_ * C_;                  // [3072][1024]
    unsigned short* wt2 = wt1 + (size_t)N3_ * C_;                // [1024][1024]
    unsigned short* xb  = wt2 + (size_t)C_ * C_;                 // [4096][1024]

    pack_bf16<<<M_ * C_ / 1024, 256, 0, stream>>>(x, xb);
    transpose_pack<<<dim3(N3_ / 32, C_ / 32), 256, 0, stream>>>(w_qkv, wt1, C_, N3_);
    transpose_pack<<<dim3(C_ / 32, C_ / 32), 256, 0, stream>>>(w_out, wt2, C_, C_);

    dim3 g1(N3_ / 128, M_ / 128);
    gemm_glds<1, 128><<<g1, 256, 0, stream>>>(xb, wt1, b_qkv, qkb, vtb, M_, N3_, C_);

    attn_mfma<<<B_ * H_ * 16, 256, 0, stream>>>(qkb, vtb, yb);

    dim3 g2(C_ / 64, M_ / 128);
    gemm_glds<0, 64><<<g2, 256, 0, stream>>>(yb, wt2, b_out, out, nullptr, M_, C_, C_);
}

// Round 8
// 192.279 us; speedup vs baseline: 1.4022x; 1.4022x over previous
//
#include <hip/hip_runtime.h>
#include <hip/hip_bf16.h>

// B=2, T=2048, C=1024, H=16, HD=64. f32 I/O; bf16 MFMA internally, f32 accum.
//
//   0) pack_bf16: x -> xb bf16; transpose_pack: w_qkv,w_out -> bf16 W^T[N][K]
//   1) gemm_glds<EPI=1,BN=128>: qkv proj; Q pre-scaled 0.125*log2e -> qk,
//      K -> qk, V -> vt[B,H,64,T] (pre-transposed).
//   2) attn_mfma: flash attention, static exp2 softmax. One 16-row tile per
//      wave (4096 waves = 16 waves/CU ceiling), blocks = 4 waves = tiles
//      4t..4t+3 (uniform nch = t+1), t descending (LPT). K/V staged by
//      glds16 with XOR-swizzled chunks (conflict-free unpadded rows).
//      NO launch_bounds cap (R7's (256,4) caused 240 MB of scratch spills).
//   3) gemm_glds<EPI=0,BN=64>: out proj, grid 512 (2 blocks/CU) -> d_out f32

#define B_ 2
#define T_ 2048
#define C_ 1024
#define H_ 16
#define HD_ 64
#define M_ (B_ * T_)      // 4096
#define N3_ (3 * C_)      // 3072
#define QK2_ 2048
#define QSCALE 0.18033688f   // 0.125 * log2(e)

typedef __attribute__((ext_vector_type(8))) short short8;
typedef __attribute__((ext_vector_type(4))) short short4v;
typedef __attribute__((ext_vector_type(4))) float floatx4;

__device__ __forceinline__ unsigned short f2b(float f) {
    __hip_bfloat16 h = __float2bfloat16(f);
    return *reinterpret_cast<unsigned short*>(&h);
}

__device__ __forceinline__ void glds16(const void* g, void* l) {
    __builtin_amdgcn_global_load_lds(
        (const __attribute__((address_space(1))) void*)g,
        (__attribute__((address_space(3))) void*)l, 16, 0, 0);
}

// f32 -> bf16 elementwise (x pack)
__global__ __launch_bounds__(256) void pack_bf16(
    const float* __restrict__ src, unsigned short* __restrict__ dst) {
    int i = (blockIdx.x * 256 + threadIdx.x) * 4;
    float4 v = *reinterpret_cast<const float4*>(src + i);
    short4v s;
    s[0] = (short)f2b(v.x); s[1] = (short)f2b(v.y);
    s[2] = (short)f2b(v.z); s[3] = (short)f2b(v.w);
    *reinterpret_cast<short4v*>(dst + i) = s;
}

// src[K][N] f32 -> dst[N][K] bf16
__global__ __launch_bounds__(256) void transpose_pack(
    const float* __restrict__ src, unsigned short* __restrict__ dst,
    int K, int N) {
    __shared__ float t[32][33];
    const int n0 = blockIdx.x * 32, k0 = blockIdx.y * 32;
    const int tx = threadIdx.x & 31, ty = threadIdx.x >> 5;
#pragma unroll
    for (int i = 0; i < 4; i++)
        t[ty + i * 8][tx] = src[(size_t)(k0 + ty + i * 8) * N + n0 + tx];
    __syncthreads();
#pragma unroll
    for (int i = 0; i < 4; i++)
        dst[(size_t)(n0 + ty + i * 8) * K + k0 + tx] = f2b(t[tx][ty + i * 8]);
}

// ---------------------------------------------------------------------------
// GEMM (m97 structure): C[M,N] = A[M,K] @ Bt^T[N,K] + bias[N]. A,Bt bf16.
// Tile 128 x BN, BK=32, 4 waves 2x2. LDS unpadded [rows][32] shorts;
// global_load_lds width=16 is exactly row-major; frag b128 reads at
// 32-short stride are conflict-free.
// ---------------------------------------------------------------------------
template<int EPI, int BN>
__global__ __launch_bounds__(256) void gemm_glds(
    const unsigned short* __restrict__ A, const unsigned short* __restrict__ Bt,
    const float* __restrict__ bias, void* __restrict__ Cp,
    unsigned short* __restrict__ vtp, int M, int N, int K) {
    constexpr int NI = BN / 32;
    __shared__ __align__(16) unsigned short Al[128 * 32];
    __shared__ __align__(16) unsigned short Bl[BN * 32];

    const int tid  = threadIdx.x;
    const int lane = tid & 63;
    const int w    = tid >> 6;
    const int c16  = lane & 15;
    const int quad = lane >> 4;
    const int n0 = blockIdx.x * BN;
    const int m0 = blockIdx.y * 128;
    const int wm = (w >> 1) * 64;
    const int wn = (w & 1) * (BN / 2);

    floatx4 acc[4][NI] = {};

    const int srow = w * 32 + (lane >> 2);
    const int scol = (lane & 3) * 8;
    const unsigned short* ag = A + (size_t)(m0 + srow) * K + scol;
    unsigned short* al0 = &Al[(w * 32) * 32];
    unsigned short* al1 = &Al[(w * 32 + 16) * 32];
    const int srowB = w * (BN / 4) + (lane >> 2);
    const unsigned short* bg = Bt + (size_t)(n0 + srowB) * K + scol;

    for (int k0 = 0; k0 < K; k0 += 32) {
        __syncthreads();
        glds16(ag + k0, al0);
        glds16(ag + k0 + (size_t)16 * K, al1);
#pragma unroll
        for (int i = 0; i < BN / 64; i++)
            glds16(bg + k0 + (size_t)(i * 16) * K,
                   &Bl[(w * (BN / 4) + i * 16) * 32]);
        __syncthreads();

        short8 af[4], bf[NI];
#pragma unroll
        for (int im = 0; im < 4; im++)
            af[im] = *reinterpret_cast<const short8*>(
                &Al[(wm + im * 16 + c16) * 32 + quad * 8]);
#pragma unroll
        for (int in = 0; in < NI; in++)
            bf[in] = *reinterpret_cast<const short8*>(
                &Bl[(wn + in * 16 + c16) * 32 + quad * 8]);
#pragma unroll
        for (int im = 0; im < 4; im++)
#pragma unroll
            for (int in = 0; in < NI; in++)
                acc[im][in] = __builtin_amdgcn_mfma_f32_16x16x32_bf16(
                    af[im], bf[in], acc[im][in], 0, 0, 0);
    }

    const int ncol = n0 + wn;
    float bv[NI];
#pragma unroll
    for (int in = 0; in < NI; in++) bv[in] = bias[ncol + in * 16 + c16];

    if (EPI == 0) {
        float* C = (float*)Cp;
#pragma unroll
        for (int im = 0; im < 4; im++)
#pragma unroll
            for (int r = 0; r < 4; r++) {
                int row = m0 + wm + im * 16 + quad * 4 + r;
#pragma unroll
                for (int in = 0; in < NI; in++)
                    C[(size_t)row * N + ncol + in * 16 + c16] =
                        acc[im][in][r] + bv[in];
            }
    } else {
        if (ncol < 2 * C_) {     // Q or K -> qk (wave-uniform branch)
            const float fac = (ncol < C_) ? QSCALE : 1.0f;
            unsigned short* qkp = (unsigned short*)Cp;
#pragma unroll
            for (int im = 0; im < 4; im++)
#pragma unroll
                for (int r = 0; r < 4; r++) {
                    int row = m0 + wm + im * 16 + quad * 4 + r;
#pragma unroll
                    for (int in = 0; in < NI; in++)
                        qkp[(size_t)row * QK2_ + ncol + in * 16 + c16] =
                            f2b((acc[im][in][r] + bv[in]) * fac);
                }
        } else {                 // V -> vt[B,H,64,T]
#pragma unroll
            for (int im = 0; im < 4; im++) {
                int row0 = m0 + wm + im * 16 + quad * 4;
                int b  = row0 >> 11;
                int t0 = row0 & (T_ - 1);
#pragma unroll
                for (int in = 0; in < NI; in++) {
                    int dfull = ncol - 2 * C_ + in * 16 + c16;  // h*64+d
                    short4v sv;
#pragma unroll
                    for (int r = 0; r < 4; r++)
                        sv[r] = (short)f2b(acc[im][in][r] + bv[in]);
                    *reinterpret_cast<short4v*>(
                        &vtp[(((size_t)(b << 10) + dfull) << 11) + t0]) = sv;
                }
            }
        }
    }
}

// ---------------------------------------------------------------------------
// One 16-row Q-tile x 64-key chunk. Kl/Vl are XOR-swizzled: row r's global
// 16B-chunk q lives at LDS chunk q^(r&7) (rows 64 shorts, unpadded).
// ---------------------------------------------------------------------------
__device__ __forceinline__ void attn_tile(
    short8 af0, short8 af1,
    const unsigned short* __restrict__ Kl,
    const unsigned short* __restrict__ Vl,
    unsigned short* __restrict__ pw,
    floatx4 O[4], float lrow[4],
    int row0, int kb, int c16, int quad) {
    const floatx4 z = {0.f, 0.f, 0.f, 0.f};
    const int sx  = c16 & 7;
    const int ch0 = (quad ^ sx) * 8;
    const int ch1 = ((quad + 4) ^ sx) * 8;
    floatx4 s[4];
#pragma unroll
    for (int nt = 0; nt < 4; nt++) {
        const int rb = (nt * 16 + c16) * 64;
        short8 k0 = *reinterpret_cast<const short8*>(&Kl[rb + ch0]);
        short8 k1 = *reinterpret_cast<const short8*>(&Kl[rb + ch1]);
        floatx4 t = __builtin_amdgcn_mfma_f32_16x16x32_bf16(af0, k0, z, 0, 0, 0);
        s[nt] = __builtin_amdgcn_mfma_f32_16x16x32_bf16(af1, k1, t, 0, 0, 0);
    }
#pragma unroll
    for (int nt = 0; nt < 4; nt++)
#pragma unroll
        for (int r = 0; r < 4; r++) {
            int key = kb + nt * 16 + c16;
            int row = row0 + quad * 4 + r;
            float p = (key <= row) ? exp2f(s[nt][r]) : 0.f;
            lrow[r] += p;
            pw[(quad * 4 + r) * 72 + nt * 16 + c16] = f2b(p);
        }
    short8 pf0 = *reinterpret_cast<const short8*>(&pw[c16 * 72 + quad * 8]);
    short8 pf1 = *reinterpret_cast<const short8*>(&pw[c16 * 72 + 32 + quad * 8]);
#pragma unroll
    for (int nt = 0; nt < 4; nt++) {
        const int rb = (nt * 16 + c16) * 64;
        short8 v0 = *reinterpret_cast<const short8*>(&Vl[rb + ch0]);
        short8 v1 = *reinterpret_cast<const short8*>(&Vl[rb + ch1]);
        floatx4 t = __builtin_amdgcn_mfma_f32_16x16x32_bf16(pf0, v0, O[nt], 0, 0, 0);
        O[nt] = __builtin_amdgcn_mfma_f32_16x16x32_bf16(pf1, v1, t, 0, 0, 0);
    }
}

// ---------------------------------------------------------------------------
// Flash attention. Block = 256 thr = 4 waves; wave w owns tile 4t+w (16 rows)
// of one (b,h); nch = t+1 is exactly uniform across the block's waves.
// Grid 1024, t descending (longest-first). K/V staged via glds16 with XOR
// chunk swizzle; P round-trips wave-private padded LDS. LDS 25.6 KB.
// ---------------------------------------------------------------------------
__global__ __launch_bounds__(256) void attn_mfma(
    const unsigned short* __restrict__ qk,
    const unsigned short* __restrict__ vt,
    unsigned short* __restrict__ y) {
    __shared__ __align__(16) unsigned short Kl[64 * 64];
    __shared__ __align__(16) unsigned short Vl[64 * 64];
    __shared__ __align__(16) unsigned short Pl[4 * 16 * 72];

    const int tid  = threadIdx.x;
    const int lane = tid & 63;
    const int w    = tid >> 6;
    const int c16  = lane & 15;
    const int quad = lane >> 4;
    const int bh = blockIdx.x & 31;
    const int t  = 31 - (blockIdx.x >> 5);   // longest-first
    const int b  = bh >> 4;
    const int h  = bh & 15;
    const int row0 = (4 * t + w) * 16;
    const int nch  = t + 1;                  // uniform across waves

    const unsigned short* qrow = qk + (size_t)b * T_ * QK2_ + h * HD_;
    const unsigned short* krow = qrow + C_;
    const unsigned short* vrow = vt + ((size_t)bh << 6) * T_;

    short8 af0 = *reinterpret_cast<const short8*>(
        qrow + (size_t)(row0 + c16) * QK2_ + quad * 8);
    short8 af1 = *reinterpret_cast<const short8*>(
        qrow + (size_t)(row0 + c16) * QK2_ + 32 + quad * 8);

    floatx4 O[4] = {};
    float lrow[4] = {};
    unsigned short* pw = &Pl[w * 16 * 72];

    const int r8 = lane >> 3;            // 0..7 within-group row
    const int sw = ((lane & 7) ^ r8) * 8;  // swizzled global chunk (shorts)

    for (int c = 0; c < nch; c++) {
        const int kb = c * 64;
        __syncthreads();                 // prev chunk's Kl/Vl reads complete
#pragma unroll
        for (int i = 0; i < 2; i++) {
            const int row = w * 16 + i * 8 + r8;
            glds16(krow + (size_t)(kb + row) * QK2_ + sw,
                   &Kl[(w * 16 + i * 8) * 64]);
            glds16(vrow + (size_t)row * T_ + kb + sw,
                   &Vl[(w * 16 + i * 8) * 64]);
        }
        __syncthreads();                 // staged data visible

        attn_tile(af0, af1, Kl, Vl, pw, O, lrow, row0, kb, c16, quad);
    }

#pragma unroll
    for (int r = 0; r < 4; r++)
#pragma unroll
        for (int off = 1; off < 16; off <<= 1)
            lrow[r] += __shfl_xor(lrow[r], off);

#pragma unroll
    for (int nt = 0; nt < 4; nt++)
#pragma unroll
        for (int r = 0; r < 4; r++) {
            float val = O[nt][r] / fmaxf(lrow[r], 1e-30f);
            y[((size_t)b * T_ + row0 + quad * 4 + r) * C_ + h * HD_ + nt * 16 + c16] =
                f2b(val);
        }
}

extern "C" void kernel_launch(void* const* d_in, const int* in_sizes, int n_in,
                              void* d_out, int out_size, void* d_ws, size_t ws_size,
                              hipStream_t stream) {
    const float* x     = (const float*)d_in[0];
    const float* w_qkv = (const float*)d_in[1];
    const float* b_qkv = (const float*)d_in[2];
    const float* w_out = (const float*)d_in[3];
    const float* b_out = (const float*)d_in[4];
    float* out = (float*)d_out;

    unsigned short* qkb = (unsigned short*)d_ws;                 // [4096][2048]
    unsigned short* vtb = qkb + (size_t)M_ * QK2_;               // [B,H,64,T]
    unsigned short* yb  = vtb + (size_t)B_ * H_ * HD_ * T_;      // [4096][1024]
    unsigned short* wt1 = yb + (size_t)M_ * C_;                  // [3072][1024]
    unsigned short* wt2 = wt1 + (size_t)N3_ * C_;                // [1024][1024]
    unsigned short* xb  = wt2 + (size_t)C_ * C_;                 // [4096][1024]

    pack_bf16<<<M_ * C_ / 1024, 256, 0, stream>>>(x, xb);
    transpose_pack<<<dim3(N3_ / 32, C_ / 32), 256, 0, stream>>>(w_qkv, wt1, C_, N3_);
    transpose_pack<<<dim3(C_ / 32, C_ / 32), 256, 0, stream>>>(w_out, wt2, C_, C_);

    dim3 g1(N3_ / 128, M_ / 128);
    gemm_glds<1, 128><<<g1, 256, 0, stream>>>(xb, wt1, b_qkv, qkb, vtb, M_, N3_, C_);

    attn_mfma<<<B_ * H_ * 32, 256, 0, stream>>>(qkb, vtb, yb);

    dim3 g2(C_ / 64, M_ / 128);
    gemm_glds<0, 64><<<g2, 256, 0, stream>>>(yb, wt2, b_out, out, nullptr, M_, C_, C_);
}

// Round 9
// 179.984 us; speedup vs baseline: 1.4980x; 1.0683x over previous
//
#include <hip/hip_runtime.h>
#include <hip/hip_bf16.h>

// B=2, T=2048, C=1024, H=16, HD=64. f32 I/O; bf16 MFMA internally, f32 accum.
//
//   0) pack_bf16: x -> xb; transpose_pack: w_qkv,w_out -> bf16 W^T[N][K]
//   1) gemm_glds<EPI=1,BN=128>: qkv proj. BK=64, XOR-swizzled LDS (conflict-
//      free b128 frag reads), glds16 staging. Q pre-scaled 0.125*log2e.
//   2) attn_mfma: flash attention, static exp2 softmax, S^T operand order
//      (P stored via ds_write_b64), mask only on the final chunk.
//   3) gemm_glds<EPI=0,BN=64>: out proj -> d_out f32

#define B_ 2
#define T_ 2048
#define C_ 1024
#define H_ 16
#define HD_ 64
#define M_ (B_ * T_)      // 4096
#define N3_ (3 * C_)      // 3072
#define QK2_ 2048
#define QSCALE 0.18033688f   // 0.125 * log2(e)

typedef __attribute__((ext_vector_type(8))) short short8;
typedef __attribute__((ext_vector_type(4))) short short4v;
typedef __attribute__((ext_vector_type(4))) float floatx4;

__device__ __forceinline__ unsigned short f2b(float f) {
    __hip_bfloat16 h = __float2bfloat16(f);
    return *reinterpret_cast<unsigned short*>(&h);
}

__device__ __forceinline__ void glds16(const void* g, void* l) {
    __builtin_amdgcn_global_load_lds(
        (const __attribute__((address_space(1))) void*)g,
        (__attribute__((address_space(3))) void*)l, 16, 0, 0);
}

// f32 -> bf16 elementwise (x pack)
__global__ __launch_bounds__(256) void pack_bf16(
    const float* __restrict__ src, unsigned short* __restrict__ dst) {
    int i = (blockIdx.x * 256 + threadIdx.x) * 4;
    float4 v = *reinterpret_cast<const float4*>(src + i);
    short4v s;
    s[0] = (short)f2b(v.x); s[1] = (short)f2b(v.y);
    s[2] = (short)f2b(v.z); s[3] = (short)f2b(v.w);
    *reinterpret_cast<short4v*>(dst + i) = s;
}

// src[K][N] f32 -> dst[N][K] bf16
__global__ __launch_bounds__(256) void transpose_pack(
    const float* __restrict__ src, unsigned short* __restrict__ dst,
    int K, int N) {
    __shared__ float t[32][33];
    const int n0 = blockIdx.x * 32, k0 = blockIdx.y * 32;
    const int tx = threadIdx.x & 31, ty = threadIdx.x >> 5;
#pragma unroll
    for (int i = 0; i < 4; i++)
        t[ty + i * 8][tx] = src[(size_t)(k0 + ty + i * 8) * N + n0 + tx];
    __syncthreads();
#pragma unroll
    for (int i = 0; i < 4; i++)
        dst[(size_t)(n0 + ty + i * 8) * K + k0 + tx] = f2b(t[tx][ty + i * 8]);
}

// ---------------------------------------------------------------------------
// GEMM: C[M,N] = A[M,K] @ Bt^T[N,K] + bias[N]. A,Bt bf16. Tile 128 x BN,
// BK=64 (32*NI/8... 16 k-iters at K=1024), 4 waves 2x2.
// LDS rows 64 shorts (128 B), XOR chunk swizzle: row r's 16B-chunk q sits at
// LDS chunk q^(r&7) -> b128 frag reads hit all 32 banks 2-way (free).
// glds16 source column carries the swizzle (dest is lane-linear, row-major).
// ---------------------------------------------------------------------------
template<int EPI, int BN>
__global__ __launch_bounds__(256) void gemm_glds(
    const unsigned short* __restrict__ A, const unsigned short* __restrict__ Bt,
    const float* __restrict__ bias, void* __restrict__ Cp,
    unsigned short* __restrict__ vtp, int M, int N, int K) {
    constexpr int NI = BN / 32;
    __shared__ __align__(16) unsigned short Al[128 * 64];
    __shared__ __align__(16) unsigned short Bl[BN * 64];

    const int tid  = threadIdx.x;
    const int lane = tid & 63;
    const int w    = tid >> 6;
    const int c16  = lane & 15;
    const int quad = lane >> 4;
    const int n0 = blockIdx.x * BN;
    const int m0 = blockIdx.y * 128;
    const int wm = (w >> 1) * 64;
    const int wn = (w & 1) * (BN / 2);

    floatx4 acc[4][NI] = {};

    const int srow = lane >> 3;                 // 0..7
    const int sch  = ((lane & 7) ^ srow) * 8;   // swizzled source chunk (shorts)
    const unsigned short* ag = A + (size_t)(m0 + w * 32 + srow) * K + sch;
    const unsigned short* bg = Bt + (size_t)(n0 + w * (BN / 4) + srow) * K + sch;

    const int s7 = c16 & 7;   // frag-read swizzle key

    for (int k0 = 0; k0 < K; k0 += 64) {
        __syncthreads();
#pragma unroll
        for (int i = 0; i < 4; i++)
            glds16(ag + k0 + (size_t)(i * 8) * K, &Al[(w * 32 + i * 8) * 64]);
#pragma unroll
        for (int i = 0; i < BN / 32; i++)
            glds16(bg + k0 + (size_t)(i * 8) * K,
                   &Bl[(w * (BN / 4) + i * 8) * 64]);
        __syncthreads();

        short8 af[4][2], bf[NI][2];
#pragma unroll
        for (int im = 0; im < 4; im++)
#pragma unroll
            for (int kk = 0; kk < 2; kk++)
                af[im][kk] = *reinterpret_cast<const short8*>(
                    &Al[(wm + im * 16 + c16) * 64 + ((kk * 4 + quad) ^ s7) * 8]);
#pragma unroll
        for (int in = 0; in < NI; in++)
#pragma unroll
            for (int kk = 0; kk < 2; kk++)
                bf[in][kk] = *reinterpret_cast<const short8*>(
                    &Bl[(wn + in * 16 + c16) * 64 + ((kk * 4 + quad) ^ s7) * 8]);
#pragma unroll
        for (int im = 0; im < 4; im++)
#pragma unroll
            for (int in = 0; in < NI; in++)
#pragma unroll
                for (int kk = 0; kk < 2; kk++)
                    acc[im][in] = __builtin_amdgcn_mfma_f32_16x16x32_bf16(
                        af[im][kk], bf[in][kk], acc[im][in], 0, 0, 0);
    }

    const int ncol = n0 + wn;
    float bv[NI];
#pragma unroll
    for (int in = 0; in < NI; in++) bv[in] = bias[ncol + in * 16 + c16];

    if (EPI == 0) {
        float* C = (float*)Cp;
#pragma unroll
        for (int im = 0; im < 4; im++)
#pragma unroll
            for (int r = 0; r < 4; r++) {
                int row = m0 + wm + im * 16 + quad * 4 + r;
#pragma unroll
                for (int in = 0; in < NI; in++)
                    C[(size_t)row * N + ncol + in * 16 + c16] =
                        acc[im][in][r] + bv[in];
            }
    } else {
        if (ncol < 2 * C_) {     // Q or K -> qk (wave-uniform branch)
            const float fac = (ncol < C_) ? QSCALE : 1.0f;
            unsigned short* qkp = (unsigned short*)Cp;
#pragma unroll
            for (int im = 0; im < 4; im++)
#pragma unroll
                for (int r = 0; r < 4; r++) {
                    int row = m0 + wm + im * 16 + quad * 4 + r;
#pragma unroll
                    for (int in = 0; in < NI; in++)
                        qkp[(size_t)row * QK2_ + ncol + in * 16 + c16] =
                            f2b((acc[im][in][r] + bv[in]) * fac);
                }
        } else {                 // V -> vt[B,H,64,T]
#pragma unroll
            for (int im = 0; im < 4; im++) {
                int row0 = m0 + wm + im * 16 + quad * 4;
                int b  = row0 >> 11;
                int t0 = row0 & (T_ - 1);
#pragma unroll
                for (int in = 0; in < NI; in++) {
                    int dfull = ncol - 2 * C_ + in * 16 + c16;  // h*64+d
                    short4v sv;
#pragma unroll
                    for (int r = 0; r < 4; r++)
                        sv[r] = (short)f2b(acc[im][in][r] + bv[in]);
                    *reinterpret_cast<short4v*>(
                        &vtp[(((size_t)(b << 10) + dfull) << 11) + t0]) = sv;
                }
            }
        }
    }
}

// ---------------------------------------------------------------------------
// One 16-row Q-tile x 64-key chunk, S^T form: QK MFMA as (K-frag, Q-frag) so
// lane (c16,quad) holds S[qrow=row0+c16][key=kb+nt*16+quad*4+r] -- 4
// consecutive keys per nt -> ds_write_b64 P stores; l is a per-lane scalar.
// MASKED only for the final chunk (earlier chunks are fully valid).
// Kl/Vl XOR-swizzled as staged (rows 64 shorts).
// ---------------------------------------------------------------------------
template<bool MASKED>
__device__ __forceinline__ void attn_tile(
    short8 af0, short8 af1,
    const unsigned short* __restrict__ Kl,
    const unsigned short* __restrict__ Vl,
    unsigned short* __restrict__ pw,
    floatx4 O[4], float& l,
    int row0, int kb, int c16, int quad) {
    const floatx4 z = {0.f, 0.f, 0.f, 0.f};
    const int sx  = c16 & 7;
    const int ch0 = (quad ^ sx) * 8;
    const int ch1 = ((quad + 4) ^ sx) * 8;
    floatx4 s[4];
#pragma unroll
    for (int nt = 0; nt < 4; nt++) {
        const int rb = (nt * 16 + c16) * 64;
        short8 k0 = *reinterpret_cast<const short8*>(&Kl[rb + ch0]);
        short8 k1 = *reinterpret_cast<const short8*>(&Kl[rb + ch1]);
        floatx4 t = __builtin_amdgcn_mfma_f32_16x16x32_bf16(k0, af0, z, 0, 0, 0);
        s[nt] = __builtin_amdgcn_mfma_f32_16x16x32_bf16(k1, af1, t, 0, 0, 0);
    }
    const int qrow = row0 + c16;
#pragma unroll
    for (int nt = 0; nt < 4; nt++) {
        short4v p4;
#pragma unroll
        for (int r = 0; r < 4; r++) {
            float p;
            if (MASKED) {
                int key = kb + nt * 16 + quad * 4 + r;
                p = (key <= qrow) ? exp2f(s[nt][r]) : 0.f;
            } else {
                p = exp2f(s[nt][r]);
            }
            l += p;
            p4[r] = (short)f2b(p);
        }
        *reinterpret_cast<short4v*>(&pw[c16 * 72 + nt * 16 + quad * 4]) = p4;
    }
    short8 pf0 = *reinterpret_cast<const short8*>(&pw[c16 * 72 + quad * 8]);
    short8 pf1 = *reinterpret_cast<const short8*>(&pw[c16 * 72 + 32 + quad * 8]);
#pragma unroll
    for (int nt = 0; nt < 4; nt++) {
        const int rb = (nt * 16 + c16) * 64;
        short8 v0 = *reinterpret_cast<const short8*>(&Vl[rb + ch0]);
        short8 v1 = *reinterpret_cast<const short8*>(&Vl[rb + ch1]);
        floatx4 t = __builtin_amdgcn_mfma_f32_16x16x32_bf16(pf0, v0, O[nt], 0, 0, 0);
        O[nt] = __builtin_amdgcn_mfma_f32_16x16x32_bf16(pf1, v1, t, 0, 0, 0);
    }
}

// ---------------------------------------------------------------------------
// Flash attention. Block = 256 thr = 4 waves; wave w owns tile 4t+w (16 rows)
// of one (b,h); nch = t+1 uniform across the block's waves. Grid 1024,
// t descending (longest-first). K/V staged via glds16 with XOR chunk swizzle.
// ---------------------------------------------------------------------------
__global__ __launch_bounds__(256) void attn_mfma(
    const unsigned short* __restrict__ qk,
    const unsigned short* __restrict__ vt,
    unsigned short* __restrict__ y) {
    __shared__ __align__(16) unsigned short Kl[64 * 64];
    __shared__ __align__(16) unsigned short Vl[64 * 64];
    __shared__ __align__(16) unsigned short Pl[4 * 16 * 72];

    const int tid  = threadIdx.x;
    const int lane = tid & 63;
    const int w    = tid >> 6;
    const int c16  = lane & 15;
    const int quad = lane >> 4;
    const int bh = blockIdx.x & 31;
    const int t  = 31 - (blockIdx.x >> 5);   // longest-first
    const int b  = bh >> 4;
    const int h  = bh & 15;
    const int row0 = (4 * t + w) * 16;
    const int nch  = t + 1;

    const unsigned short* qrow = qk + (size_t)b * T_ * QK2_ + h * HD_;
    const unsigned short* krow = qrow + C_;
    const unsigned short* vrow = vt + ((size_t)bh << 6) * T_;

    short8 af0 = *reinterpret_cast<const short8*>(
        qrow + (size_t)(row0 + c16) * QK2_ + quad * 8);
    short8 af1 = *reinterpret_cast<const short8*>(
        qrow + (size_t)(row0 + c16) * QK2_ + 32 + quad * 8);

    floatx4 O[4] = {};
    float l = 0.f;
    unsigned short* pw = &Pl[w * 16 * 72];

    const int r8 = lane >> 3;
    const int sw = ((lane & 7) ^ r8) * 8;

    for (int c = 0; c < nch; c++) {
        const int kb = c * 64;
        __syncthreads();
#pragma unroll
        for (int i = 0; i < 2; i++) {
            const int row = w * 16 + i * 8 + r8;
            glds16(krow + (size_t)(kb + row) * QK2_ + sw,
                   &Kl[(w * 16 + i * 8) * 64]);
            glds16(vrow + (size_t)row * T_ + kb + sw,
                   &Vl[(w * 16 + i * 8) * 64]);
        }
        __syncthreads();

        if (c + 1 < nch)
            attn_tile<false>(af0, af1, Kl, Vl, pw, O, l, row0, kb, c16, quad);
        else
            attn_tile<true>(af0, af1, Kl, Vl, pw, O, l, row0, kb, c16, quad);
    }

    // l currently per-lane (qrow = row0 + c16, keys split across quads)
    l += __shfl_xor(l, 16);
    l += __shfl_xor(l, 32);
    float lr[4];
#pragma unroll
    for (int r = 0; r < 4; r++)
        lr[r] = __shfl(l, quad * 4 + r);     // l for qrow = row0+quad*4+r

#pragma unroll
    for (int nt = 0; nt < 4; nt++)
#pragma unroll
        for (int r = 0; r < 4; r++) {
            float val = O[nt][r] / fmaxf(lr[r], 1e-30f);
            y[((size_t)b * T_ + row0 + quad * 4 + r) * C_ + h * HD_ + nt * 16 + c16] =
                f2b(val);
        }
}

extern "C" void kernel_launch(void* const* d_in, const int* in_sizes, int n_in,
                              void* d_out, int out_size, void* d_ws, size_t ws_size,
                              hipStream_t stream) {
    const float* x     = (const float*)d_in[0];
    const float* w_qkv = (const float*)d_in[1];
    const float* b_qkv = (const float*)d_in[2];
    const float* w_out = (const float*)d_in[3];
    const float* b_out = (const float*)d_in[4];
    float* out = (float*)d_out;

    unsigned short* qkb = (unsigned short*)d_ws;                 // [4096][2048]
    unsigned short* vtb = qkb + (size_t)M_ * QK2_;               // [B,H,64,T]
    unsigned short* yb  = vtb + (size_t)B_ * H_ * HD_ * T_;      // [4096][1024]
    unsigned short* wt1 = yb + (size_t)M_ * C_;                  // [3072][1024]
    unsigned short* wt2 = wt1 + (size_t)N3_ * C_;                // [1024][1024]
    unsigned short* xb  = wt2 + (size_t)C_ * C_;                 // [4096][1024]

    pack_bf16<<<M_ * C_ / 1024, 256, 0, stream>>>(x, xb);
    transpose_pack<<<dim3(N3_ / 32, C_ / 32), 256, 0, stream>>>(w_qkv, wt1, C_, N3_);
    transpose_pack<<<dim3(C_ / 32, C_ / 32), 256, 0, stream>>>(w_out, wt2, C_, C_);

    dim3 g1(N3_ / 128, M_ / 128);
    gemm_glds<1, 128><<<g1, 256, 0, stream>>>(xb, wt1, b_qkv, qkb, vtb, M_, N3_, C_);

    attn_mfma<<<B_ * H_ * 32, 256, 0, stream>>>(qkb, vtb, yb);

    dim3 g2(C_ / 64, M_ / 128);
    gemm_glds<0, 64><<<g2, 256, 0, stream>>>(yb, wt2, b_out, out, nullptr, M_, C_, C_);
}